// Round 1
// 120.176 us; speedup vs baseline: 2.0594x; 2.0594x over previous
//
#include <hip/hip_runtime.h>

// Sinkhorn via separable kernel: K = exp(-C/eps) = G (x) G  (kron), with
// G[a][b] = exp(-100 * C1d[a][b]) and C1d[a][b] = C[(a*48)*2304 + b*48]
// (exact 1D slice of the provided cost matrix -> same rounded dy^2 as ref).
// K.x = y-conv(G, x-conv(G, x)): 2 x (48x48 @ 48x48) per pass instead of a
// 2304^2 matvec (24x fewer FLOPs, K never materialized).
// Cost pass: K o C = H(x)G + G(x)H with H = G * C1d.
// One block per batch (32 blocks), whole 10-half-pass chain in one kernel,
// all state in LDS ([48][49] padded: column reads are 2-way = free).
// 6 waves x 8 output rows; G/H read wave-uniform (s_load path via
// readfirstlane-forced scalar wave id), data read lane-spread b32.

#define SZ 48
#define SN 2304          // 48*48
#define LD 49            // padded LDS row stride
#define NBAT 32
#define NTHR 384         // 6 waves
#define YB 8             // output rows per wave (6*8 = 48)

__global__ __launch_bounds__(256) void k_pre(const float* __restrict__ C,
                                             float* __restrict__ G,
                                             float* __restrict__ H) {
    for (int idx = threadIdx.x; idx < SN; idx += 256) {
        const int a = idx / SZ;
        const int c = idx - a * SZ;
        const float cv = C[(size_t)a * SZ * SN + (size_t)c * SZ];
        const float g = expf(-100.f * cv);
        G[idx] = g;
        H[idx] = g * cv;
    }
}

__global__ __launch_bounds__(NTHR) void k_sink(const float* __restrict__ pred,
                                               const float* __restrict__ tgt,
                                               const float* __restrict__ Gm,
                                               const float* __restrict__ Hm,
                                               float* __restrict__ out) {
    __shared__ float Fa[SZ * LD];    // alpha scaling (init 1)
    __shared__ float Fb[SZ * LD];    // beta scaling (init 1)
    __shared__ float Fms[SZ * LD];   // mass_source; reused as T2 in final
    __shared__ float Fmt[SZ * LD];   // mass_target
    __shared__ float T[SZ * LD];     // conv intermediate
    __shared__ float red[16];

    const int t = threadIdx.x;
    const int b = blockIdx.x;
    const int l = t & 63;
    const int w = __builtin_amdgcn_readfirstlane(t >> 6);  // scalar wave id
    const int r0 = w * YB;                                 // this wave's output rows

    // ---- init: load channel-0 planes, sum, normalize ----
    const float* __restrict__ pg = pred + (size_t)b * 3 * SN;
    const float* __restrict__ tg = tgt + (size_t)b * 3 * SN;
    float sp = 0.f, st = 0.f;
    for (int i = t; i < SN; i += NTHR) {
        const float vp = pg[i] + 1e-9f;
        const float vt = tg[i] + 1e-9f;
        const int y = i / SZ, x = i - y * SZ;
        Fms[y * LD + x] = vp;
        Fmt[y * LD + x] = vt;
        sp += vp; st += vt;
    }
    #pragma unroll
    for (int off = 32; off; off >>= 1) {
        sp += __shfl_down(sp, off);
        st += __shfl_down(st, off);
    }
    if (l == 0) { red[w] = sp; red[8 + w] = st; }
    __syncthreads();
    float ps = 0.f, ts = 0.f;
    #pragma unroll
    for (int k = 0; k < 6; ++k) { ps += red[k]; ts += red[8 + k]; }
    for (int i = t; i < SN; i += NTHR) {
        const int y = i / SZ, x = i - y * SZ;
        Fms[y * LD + x] /= ps;
        Fmt[y * LD + x] /= ts;
        Fa[y * LD + x] = 1.f;
        Fb[y * LD + x] = 1.f;
    }
    __syncthreads();

    // ---- 10 half-iterations (5 alpha-updates, 5 beta-updates) ----
    for (int p = 0; p < 10; ++p) {
        float* __restrict__ src = (p & 1) ? Fa : Fb;
        float* __restrict__ dst = (p & 1) ? Fb : Fa;
        const float* __restrict__ mv = (p & 1) ? Fmt : Fms;

        // step1 (x-conv): T[y][xi] = sum_j G[xi][j] * src[y][j]  (G symmetric)
        if (l < SZ) {
            float acc[YB];
            #pragma unroll
            for (int k = 0; k < YB; ++k) acc[k] = 0.f;
            #pragma unroll 4
            for (int j = 0; j < SZ; ++j) {
                const float v = src[l * LD + j];           // column-of-row read, 2-way max
                #pragma unroll
                for (int k = 0; k < YB; ++k)
                    acc[k] = fmaf(Gm[j * SZ + r0 + k], v, acc[k]);   // uniform -> s_load_dwordx8
            }
            #pragma unroll
            for (int k = 0; k < YB; ++k) T[l * LD + r0 + k] = acc[k];
        }
        __syncthreads();

        // step2 (y-conv) + fused scaling update:
        // S[yi][x] = sum_j G[yi][j]*T[j][x]; dst = mv*dst/(dst*S + 1e-6)
        if (l < SZ) {
            float acc[YB];
            #pragma unroll
            for (int k = 0; k < YB; ++k) acc[k] = 0.f;
            #pragma unroll 4
            for (int j = 0; j < SZ; ++j) {
                const float v = T[j * LD + l];             // row read, conflict-free
                #pragma unroll
                for (int k = 0; k < YB; ++k)
                    acc[k] = fmaf(Gm[j * SZ + r0 + k], v, acc[k]);
            }
            #pragma unroll
            for (int k = 0; k < YB; ++k) {
                const int idx = (r0 + k) * LD + l;
                const float yo = dst[idx];
                dst[idx] = mv[idx] * yo / (yo * acc[k] + 1e-6f);
            }
        }
        __syncthreads();
    }

    // ---- final: cost = sum Fa .* ((H(x)G + G(x)H) applied to Fb) ----
    // T1 = G-x-conv(beta), T2 = H-x-conv(beta)  (T2 stored in Fms, now free)
    if (l < SZ) {
        float t1[YB], t2[YB];
        #pragma unroll
        for (int k = 0; k < YB; ++k) { t1[k] = 0.f; t2[k] = 0.f; }
        #pragma unroll 2
        for (int j = 0; j < SZ; ++j) {
            const float v = Fb[l * LD + j];
            #pragma unroll
            for (int k = 0; k < YB; ++k) {
                t1[k] = fmaf(Gm[j * SZ + r0 + k], v, t1[k]);
                t2[k] = fmaf(Hm[j * SZ + r0 + k], v, t2[k]);
            }
        }
        #pragma unroll
        for (int k = 0; k < YB; ++k) {
            T[l * LD + r0 + k]   = t1[k];
            Fms[l * LD + r0 + k] = t2[k];
        }
    }
    __syncthreads();

    // U[yi][x] = sum_j H[yi][j]*T1[j][x] + G[yi][j]*T2[j][x]; part = Fa . U
    float part = 0.f;
    if (l < SZ) {
        float u[YB];
        #pragma unroll
        for (int k = 0; k < YB; ++k) u[k] = 0.f;
        #pragma unroll 2
        for (int j = 0; j < SZ; ++j) {
            const float v1 = T[j * LD + l];
            const float v2 = Fms[j * LD + l];
            #pragma unroll
            for (int k = 0; k < YB; ++k) {
                u[k] = fmaf(Hm[j * SZ + r0 + k], v1, u[k]);
                u[k] = fmaf(Gm[j * SZ + r0 + k], v2, u[k]);
            }
        }
        #pragma unroll
        for (int k = 0; k < YB; ++k)
            part = fmaf(Fa[(r0 + k) * LD + l], u[k], part);
    }
    #pragma unroll
    for (int off = 32; off; off >>= 1) part += __shfl_down(part, off);
    if (l == 0) red[w] = part;
    __syncthreads();
    if (t == 0) {
        float c = 0.f;
        #pragma unroll
        for (int k = 0; k < 6; ++k) c += red[k];
        out[b] = c;
    }
}

extern "C" void kernel_launch(void* const* d_in, const int* in_sizes, int n_in,
                              void* d_out, int out_size, void* d_ws, size_t ws_size,
                              hipStream_t stream) {
    const float* pred = (const float*)d_in[0];
    const float* tgt  = (const float*)d_in[1];
    const float* C    = (const float*)d_in[2];
    float* G = (float*)d_ws;          // 2304 floats
    float* H = G + SN;                // 2304 floats

    k_pre<<<1, 256, 0, stream>>>(C, G, H);
    k_sink<<<NBAT, NTHR, 0, stream>>>(pred, tgt, G, H, (float*)d_out);
}

// Round 2
// 101.880 us; speedup vs baseline: 2.4292x; 1.1796x over previous
//
#include <hip/hip_runtime.h>

// Sinkhorn via separable kernel: K = exp(-C/eps) = G (x) G (kron), with
// G[a][b] = exp(-100 * C1d[a][b]) read as exact 1D slices of the provided C
// (preserves reference's rounded dy^2). K.x = y-conv(G, x-conv(G, x)).
// Cost pass: K o C = H(x)G + G(x)H with H = G * C1d.
// One block per batch (32 blocks), whole chain in one kernel, state in LDS
// ([48][49] padded rows: both row- and column-direction b32 reads are at
// worst 2-way bank aliased = free).
// This round: 12 waves x 4 rows (3 waves/SIMD, was 1.5) to hide ds_read /
// s_load latency; pass 0 folded analytically (beta==1 -> S0 = gs[y]*gs[x]),
// saving 2 conv steps + 2 barriers; k_pre spread over 9 blocks.

#define SZ 48
#define SN 2304          // 48*48
#define LD 49            // padded LDS row stride
#define NBAT 32
#define NTHR 768         // 12 waves
#define NW 12
#define YB 4             // output rows per wave (12*4 = 48)

__global__ __launch_bounds__(256) void k_pre(const float* __restrict__ C,
                                             float* __restrict__ G,
                                             float* __restrict__ H) {
    const int idx = blockIdx.x * 256 + threadIdx.x;   // 9*256 = 2304 exactly
    const int a = idx / SZ;
    const int c = idx - a * SZ;
    const float cv = C[(size_t)a * SZ * SN + (size_t)c * SZ];
    const float g = expf(-100.f * cv);
    G[idx] = g;
    H[idx] = g * cv;
}

__global__ __launch_bounds__(NTHR) void k_sink(const float* __restrict__ pred,
                                               const float* __restrict__ tgt,
                                               const float* __restrict__ Gm,
                                               const float* __restrict__ Hm,
                                               float* __restrict__ out) {
    __shared__ float Fa[SZ * LD];    // alpha scaling
    __shared__ float Fb[SZ * LD];    // beta scaling (init 1)
    __shared__ float Fms[SZ * LD];   // mass_source; reused as T2 in final
    __shared__ float Fmt[SZ * LD];   // mass_target
    __shared__ float T[SZ * LD];     // conv intermediate
    __shared__ float gsl[SZ];        // row sums of G (for folded pass 0)
    __shared__ float red[32];

    const int t = threadIdx.x;
    const int b = blockIdx.x;
    const int l = t & 63;
    const int w = __builtin_amdgcn_readfirstlane(t >> 6);  // scalar wave id
    const int r0 = w * YB;                                 // wave's output rows

    // ---- init: G row sums, load channel-0 planes, sum, normalize ----
    if (t < SZ) {
        float s = 0.f;
        #pragma unroll 8
        for (int j = 0; j < SZ; ++j) s += Gm[t * SZ + j];
        gsl[t] = s;
    }
    const float* __restrict__ pg = pred + (size_t)b * 3 * SN;
    const float* __restrict__ tg = tgt + (size_t)b * 3 * SN;
    float sp = 0.f, st = 0.f;
    for (int i = t; i < SN; i += NTHR) {
        const float vp = pg[i] + 1e-9f;
        const float vt = tg[i] + 1e-9f;
        const int y = i / SZ, x = i - y * SZ;
        Fms[y * LD + x] = vp;
        Fmt[y * LD + x] = vt;
        sp += vp; st += vt;
    }
    #pragma unroll
    for (int off = 32; off; off >>= 1) {
        sp += __shfl_down(sp, off);
        st += __shfl_down(st, off);
    }
    if (l == 0) { red[w] = sp; red[16 + w] = st; }
    __syncthreads();
    float ps = 0.f, ts = 0.f;
    #pragma unroll
    for (int k = 0; k < NW; ++k) { ps += red[k]; ts += red[16 + k]; }
    // folded pass 0: Fa = m_src / (gs[y]*gs[x] + 1e-6), Fb = 1
    for (int i = t; i < SN; i += NTHR) {
        const int y = i / SZ, x = i - y * SZ;
        const float ms = Fms[y * LD + x] / ps;
        Fms[y * LD + x] = ms;
        Fmt[y * LD + x] /= ts;
        Fa[y * LD + x] = ms / (gsl[y] * gsl[x] + 1e-6f);
        Fb[y * LD + x] = 1.f;
    }
    __syncthreads();

    // ---- remaining 9 half-iterations (p=1..9) ----
    for (int p = 1; p < 10; ++p) {
        float* __restrict__ src = (p & 1) ? Fa : Fb;
        float* __restrict__ dst = (p & 1) ? Fb : Fa;
        const float* __restrict__ mv = (p & 1) ? Fmt : Fms;

        // step1 (x-conv): T[y][xi] = sum_j G[xi][j] * src[y][j]  (G symmetric)
        if (l < SZ) {
            float acc[YB];
            #pragma unroll
            for (int k = 0; k < YB; ++k) acc[k] = 0.f;
            #pragma unroll 8
            for (int j = 0; j < SZ; ++j) {
                const float v = src[l * LD + j];            // 2-way max = free
                #pragma unroll
                for (int k = 0; k < YB; ++k)
                    acc[k] = fmaf(Gm[j * SZ + r0 + k], v, acc[k]);  // s_load_dwordx4
            }
            #pragma unroll
            for (int k = 0; k < YB; ++k) T[l * LD + r0 + k] = acc[k];
        }
        __syncthreads();

        // step2 (y-conv) + fused scaling update:
        // S[yi][x] = sum_j G[yi][j]*T[j][x]; dst = mv*dst/(dst*S + 1e-6)
        if (l < SZ) {
            float acc[YB];
            #pragma unroll
            for (int k = 0; k < YB; ++k) acc[k] = 0.f;
            #pragma unroll 8
            for (int j = 0; j < SZ; ++j) {
                const float v = T[j * LD + l];              // conflict-free
                #pragma unroll
                for (int k = 0; k < YB; ++k)
                    acc[k] = fmaf(Gm[j * SZ + r0 + k], v, acc[k]);
            }
            #pragma unroll
            for (int k = 0; k < YB; ++k) {
                const int idx = (r0 + k) * LD + l;
                const float yo = dst[idx];
                dst[idx] = mv[idx] * yo / (yo * acc[k] + 1e-6f);
            }
        }
        __syncthreads();
    }

    // ---- final: cost = sum Fa .* ((H(x)G + G(x)H) applied to Fb) ----
    // T1 = G-x-conv(beta), T2 = H-x-conv(beta)  (T2 stored in Fms, now free)
    if (l < SZ) {
        float t1[YB], t2[YB];
        #pragma unroll
        for (int k = 0; k < YB; ++k) { t1[k] = 0.f; t2[k] = 0.f; }
        #pragma unroll 4
        for (int j = 0; j < SZ; ++j) {
            const float v = Fb[l * LD + j];
            #pragma unroll
            for (int k = 0; k < YB; ++k) {
                t1[k] = fmaf(Gm[j * SZ + r0 + k], v, t1[k]);
                t2[k] = fmaf(Hm[j * SZ + r0 + k], v, t2[k]);
            }
        }
        #pragma unroll
        for (int k = 0; k < YB; ++k) {
            T[l * LD + r0 + k]   = t1[k];
            Fms[l * LD + r0 + k] = t2[k];
        }
    }
    __syncthreads();

    // U[yi][x] = sum_j H[yi][j]*T1[j][x] + G[yi][j]*T2[j][x]; part = Fa . U
    float part = 0.f;
    if (l < SZ) {
        float u[YB];
        #pragma unroll
        for (int k = 0; k < YB; ++k) u[k] = 0.f;
        #pragma unroll 4
        for (int j = 0; j < SZ; ++j) {
            const float v1 = T[j * LD + l];
            const float v2 = Fms[j * LD + l];
            #pragma unroll
            for (int k = 0; k < YB; ++k) {
                u[k] = fmaf(Hm[j * SZ + r0 + k], v1, u[k]);
                u[k] = fmaf(Gm[j * SZ + r0 + k], v2, u[k]);
            }
        }
        #pragma unroll
        for (int k = 0; k < YB; ++k)
            part = fmaf(Fa[(r0 + k) * LD + l], u[k], part);
    }
    #pragma unroll
    for (int off = 32; off; off >>= 1) part += __shfl_down(part, off);
    if (l == 0) red[w] = part;
    __syncthreads();
    if (t == 0) {
        float c = 0.f;
        #pragma unroll
        for (int k = 0; k < NW; ++k) c += red[k];
        out[b] = c;
    }
}

extern "C" void kernel_launch(void* const* d_in, const int* in_sizes, int n_in,
                              void* d_out, int out_size, void* d_ws, size_t ws_size,
                              hipStream_t stream) {
    const float* pred = (const float*)d_in[0];
    const float* tgt  = (const float*)d_in[1];
    const float* C    = (const float*)d_in[2];
    float* G = (float*)d_ws;          // 2304 floats
    float* H = G + SN;                // 2304 floats

    k_pre<<<9, 256, 0, stream>>>(C, G, H);
    k_sink<<<NBAT, NTHR, 0, stream>>>(pred, tgt, G, H, (float*)d_out);
}